// Round 1
// baseline (1735.750 us; speedup 1.0000x reference)
//
#include <hip/hip_runtime.h>

#define HH 256
#define WW 256
#define CC 64
#define FF 128
#define NN 8
#define OUTC 384           // 3*C sep + C lap + F learned
#define HW (HH * WW)

__device__ __forceinline__ int clampi(int v, int lo, int hi) {
    return v < lo ? lo : (v > hi ? hi : v);
}

// ---------------------------------------------------------------------------
// Kernel 1: depthwise fixed filters (identity, sobel_y, sobel_x, laplacian)
// block = 256 threads = 4 rows x 64 float4-columns for one (n, c)
// ---------------------------------------------------------------------------
__global__ __launch_bounds__(256) void dw_kernel(const float* __restrict__ x,
                                                 float* __restrict__ out) {
    int blk = blockIdx.x;                 // ((n*CC + c) * 64 + y4)
    int y4 = blk & 63;
    int nc = blk >> 6;
    int c = nc & (CC - 1);
    int n = nc >> 6;

    int t = threadIdx.x;
    int ry = t >> 6;                      // 0..3
    int col = (t & 63) * 4;               // 0..252
    int y = y4 * 4 + ry;

    const float* xp = x + ((size_t)(n * CC + c)) * HW;
    int ym = y == 0 ? 0 : y - 1;
    int yp = y == HH - 1 ? HH - 1 : y + 1;
    int cl = col == 0 ? 0 : col - 1;
    int cr = (col + 4 > WW - 1) ? WW - 1 : col + 4;

    float4 top = *(const float4*)(xp + (size_t)ym * WW + col);
    float4 mid = *(const float4*)(xp + (size_t)y  * WW + col);
    float4 bot = *(const float4*)(xp + (size_t)yp * WW + col);
    float tl = xp[(size_t)ym * WW + cl], tr = xp[(size_t)ym * WW + cr];
    float ml = xp[(size_t)y  * WW + cl], mr = xp[(size_t)y  * WW + cr];
    float bl = xp[(size_t)yp * WW + cl], br = xp[(size_t)yp * WW + cr];

    float tv[6] = {tl, top.x, top.y, top.z, top.w, tr};
    float mv[6] = {ml, mid.x, mid.y, mid.z, mid.w, mr};
    float bv[6] = {bl, bot.x, bot.y, bot.z, bot.w, br};

    float o0[4], o1[4], o2[4], o3[4];
#pragma unroll
    for (int j = 0; j < 4; ++j) {
        float tL = tv[j], tC = tv[j + 1], tR = tv[j + 2];
        float mL = mv[j], mC = mv[j + 1], mR = mv[j + 2];
        float bL = bv[j], bC = bv[j + 1], bR = bv[j + 2];
        o0[j] = mC;                                            // identity
        o1[j] = (tL + 2.0f * tC + tR) - (bL + 2.0f * bC + bR); // sobel_y
        o2[j] = (tL - tR) + 2.0f * (mL - mR) + (bL - bR);      // sobel_x
        o3[j] = 4.0f * mC - tC - bC - mL - mR;                 // laplacian
    }

    size_t obase = ((size_t)n * OUTC) * HW + (size_t)y * WW + col;
    *(float4*)(out + obase + (size_t)(c * 3 + 0) * HW) = make_float4(o0[0], o0[1], o0[2], o0[3]);
    *(float4*)(out + obase + (size_t)(c * 3 + 1) * HW) = make_float4(o1[0], o1[1], o1[2], o1[3]);
    *(float4*)(out + obase + (size_t)(c * 3 + 2) * HW) = make_float4(o2[0], o2[1], o2[2], o2[3]);
    *(float4*)(out + obase + (size_t)(192 + c)   * HW) = make_float4(o3[0], o3[1], o3[2], o3[3]);
}

// ---------------------------------------------------------------------------
// Kernel 2: learned dense 3x3 conv (fp32 VALU, register-tiled)
// block = 256 threads: 16 f-groups (8 f each) x 16 pixel-groups (4 px each)
// block computes an 8x8 spatial tile x all 128 output channels
// ---------------------------------------------------------------------------
#define CCH 8   // input-channel chunk staged in LDS

__global__ __launch_bounds__(256) void learned_kernel(const float* __restrict__ x,
                                                      const float* __restrict__ Wl,
                                                      const float* __restrict__ bl,
                                                      float* __restrict__ out) {
    __shared__ float xt[CCH][10][10];     // 3.2 KB  (8x8 tile + halo)
    __shared__ float wt[CCH * 9][FF];     // 36 KB   (wt[c*9+t][f])

    int blk = blockIdx.x;                 // n * 1024 + ty*32 + tx
    int tile = blk & 1023;
    int n = blk >> 10;
    int ty = tile >> 5, tx = tile & 31;
    int y0 = ty * 8, x0 = tx * 8;

    int tid = threadIdx.x;
    int pg = tid & 15;                    // pixel group: yy = pg>>1, xx0 = (pg&1)*4
    int fg = tid >> 4;                    // f group: f0 = fg*8
    int yy = pg >> 1;
    int xx0 = (pg & 1) * 4;
    int f0 = fg * 8;

    float acc[4][8];
#pragma unroll
    for (int j = 0; j < 4; ++j)
#pragma unroll
        for (int k = 0; k < 8; ++k) acc[j][k] = 0.0f;

    const float* xbase = x + (size_t)n * CC * HW;

    for (int c0 = 0; c0 < CC; c0 += CCH) {
        __syncthreads();
        // stage input slab with replicate-pad halo
        for (int e = tid; e < CCH * 100; e += 256) {
            int cc = e / 100;
            int r = e - cc * 100;
            int ryy = r / 10, rxx = r - (r / 10) * 10;
            int gy = clampi(y0 - 1 + ryy, 0, HH - 1);
            int gx = clampi(x0 - 1 + rxx, 0, WW - 1);
            xt[cc][ryy][rxx] = xbase[((size_t)(c0 + cc)) * HW + (size_t)gy * WW + gx];
        }
        // stage weight slab: wt[cc*9+t][f] = W[f][c0+cc][t]
        for (int e = tid; e < CCH * 9 * FF; e += 256) {
            int f = e & (FF - 1);
            int ct = e >> 7;              // 0..71
            int cc = ct / 9;
            int tt = ct - cc * 9;
            wt[ct][f] = Wl[(size_t)f * (CC * 9) + (size_t)(c0 + cc) * 9 + tt];
        }
        __syncthreads();

#pragma unroll
        for (int cc = 0; cc < CCH; ++cc) {
#pragma unroll
            for (int dy = 0; dy < 3; ++dy) {
                float xwin[6];
#pragma unroll
                for (int j = 0; j < 6; ++j) xwin[j] = xt[cc][yy + dy][xx0 + j];
#pragma unroll
                for (int dx = 0; dx < 3; ++dx) {
                    float w8[8];
#pragma unroll
                    for (int k = 0; k < 8; ++k) w8[k] = wt[cc * 9 + dy * 3 + dx][f0 + k];
#pragma unroll
                    for (int j = 0; j < 4; ++j)
#pragma unroll
                        for (int k = 0; k < 8; ++k)
                            acc[j][k] = fmaf(xwin[j + dx], w8[k], acc[j][k]);
                }
            }
        }
    }

    // epilogue: bias + store (learned channels start at 256)
    size_t obase = ((size_t)n * OUTC + 256 + f0) * HW + (size_t)(y0 + yy) * WW + (x0 + xx0);
#pragma unroll
    for (int k = 0; k < 8; ++k) {
        float b = bl[f0 + k];
        float4 v = make_float4(acc[0][k] + b, acc[1][k] + b, acc[2][k] + b, acc[3][k] + b);
        *(float4*)(out + obase + (size_t)k * HW) = v;
    }
}

extern "C" void kernel_launch(void* const* d_in, const int* in_sizes, int n_in,
                              void* d_out, int out_size, void* d_ws, size_t ws_size,
                              hipStream_t stream) {
    const float* x  = (const float*)d_in[0];
    const float* Wl = (const float*)d_in[1];
    const float* bl = (const float*)d_in[2];
    float* out = (float*)d_out;

    dw_kernel<<<NN * CC * (HH / 4), 256, 0, stream>>>(x, out);
    learned_kernel<<<NN * 1024, 256, 0, stream>>>(x, Wl, bl, out);
}

// Round 2
// 314.978 us; speedup vs baseline: 5.5107x; 5.5107x over previous
//
#include <hip/hip_runtime.h>

#define HH 256
#define WW 256
#define CC 64
#define FF 128
#define NN 8
#define OUTC 384           // 3*C sep + C lap + F learned
#define HW (HH * WW)

typedef __attribute__((ext_vector_type(8))) short bf16x8;
typedef __attribute__((ext_vector_type(4))) float f32x4;

__device__ __forceinline__ int clampi(int v, int lo, int hi) {
    return v < lo ? lo : (v > hi ? hi : v);
}

// round-to-nearest-even fp32 -> bf16
static __device__ __forceinline__ unsigned short f2bf(float x) {
    unsigned u = __builtin_bit_cast(unsigned, x);
    u += 0x7FFFu + ((u >> 16) & 1u);
    return (unsigned short)(u >> 16);
}
static __device__ __forceinline__ unsigned packbf(float a, float b) {
    return (unsigned)f2bf(a) | ((unsigned)f2bf(b) << 16);
}

// ---------------------------------------------------------------------------
// Kernel 0: W[f][c][3][3] fp32 -> ws bf16 [tap][f][c]   (9*128*64 elems)
// ---------------------------------------------------------------------------
__global__ __launch_bounds__(256) void wT_kernel(const float* __restrict__ Wl,
                                                 unsigned* __restrict__ wsW) {
    int e = blockIdx.x * 256 + threadIdx.x;     // over 9*128*32 = 36864 pairs
    if (e >= 9 * 128 * 32) return;
    int t = e >> 12;
    int rem = e & 4095;
    int f = rem >> 5;
    int c2 = rem & 31;
    float a = Wl[(size_t)f * 576 + (size_t)(2 * c2) * 9 + t];
    float b = Wl[(size_t)f * 576 + (size_t)(2 * c2 + 1) * 9 + t];
    wsW[t * 4096 + f * 32 + c2] = packbf(a, b);
}

// ---------------------------------------------------------------------------
// Kernel 1: depthwise fixed filters (identity, sobel_y, sobel_x, laplacian)
// ---------------------------------------------------------------------------
__global__ __launch_bounds__(256) void dw_kernel(const float* __restrict__ x,
                                                 float* __restrict__ out) {
    int blk = blockIdx.x;                 // ((n*CC + c) * 64 + y4)
    int y4 = blk & 63;
    int nc = blk >> 6;
    int c = nc & (CC - 1);
    int n = nc >> 6;

    int t = threadIdx.x;
    int ry = t >> 6;
    int col = (t & 63) * 4;
    int y = y4 * 4 + ry;

    const float* xp = x + ((size_t)(n * CC + c)) * HW;
    int ym = y == 0 ? 0 : y - 1;
    int yp = y == HH - 1 ? HH - 1 : y + 1;
    int cl = col == 0 ? 0 : col - 1;
    int cr = (col + 4 > WW - 1) ? WW - 1 : col + 4;

    float4 top = *(const float4*)(xp + (size_t)ym * WW + col);
    float4 mid = *(const float4*)(xp + (size_t)y  * WW + col);
    float4 bot = *(const float4*)(xp + (size_t)yp * WW + col);
    float tl = xp[(size_t)ym * WW + cl], tr = xp[(size_t)ym * WW + cr];
    float ml = xp[(size_t)y  * WW + cl], mr = xp[(size_t)y  * WW + cr];
    float bl = xp[(size_t)yp * WW + cl], br = xp[(size_t)yp * WW + cr];

    float tv[6] = {tl, top.x, top.y, top.z, top.w, tr};
    float mv[6] = {ml, mid.x, mid.y, mid.z, mid.w, mr};
    float bv[6] = {bl, bot.x, bot.y, bot.z, bot.w, br};

    float o0[4], o1[4], o2[4], o3[4];
#pragma unroll
    for (int j = 0; j < 4; ++j) {
        float tL = tv[j], tC = tv[j + 1], tR = tv[j + 2];
        float mL = mv[j], mC = mv[j + 1], mR = mv[j + 2];
        float bL = bv[j], bC = bv[j + 1], bR = bv[j + 2];
        o0[j] = mC;
        o1[j] = (tL + 2.0f * tC + tR) - (bL + 2.0f * bC + bR);
        o2[j] = (tL - tR) + 2.0f * (mL - mR) + (bL - bR);
        o3[j] = 4.0f * mC - tC - bC - mL - mR;
    }

    size_t obase = ((size_t)n * OUTC) * HW + (size_t)y * WW + col;
    *(float4*)(out + obase + (size_t)(c * 3 + 0) * HW) = make_float4(o0[0], o0[1], o0[2], o0[3]);
    *(float4*)(out + obase + (size_t)(c * 3 + 1) * HW) = make_float4(o1[0], o1[1], o1[2], o1[3]);
    *(float4*)(out + obase + (size_t)(c * 3 + 2) * HW) = make_float4(o2[0], o2[1], o2[2], o2[3]);
    *(float4*)(out + obase + (size_t)(192 + c)   * HW) = make_float4(o3[0], o3[1], o3[2], o3[3]);
}

// ---------------------------------------------------------------------------
// Kernel 2: learned dense 3x3 conv via bf16 MFMA, tap-decomposed implicit GEMM
// block = 512 thr (8 waves). out tile = 16x16 px * 128 f. D[f][px].
// LDS: x-tile [324 pix][64 ch] bf16 (XOR-swizzled), W per-tap [128 f][64 c] x2
// ---------------------------------------------------------------------------
__global__ __launch_bounds__(512) void learned_kernel(const float* __restrict__ x,
                                                      const unsigned short* __restrict__ wsW,
                                                      const float* __restrict__ bl,
                                                      float* __restrict__ out) {
    __shared__ __align__(16) unsigned char lds_x[324 * 128];      // 41472 B
    __shared__ __align__(16) unsigned char lds_w[2][128 * 128];   // 32768 B

    int blk = blockIdx.x;                 // n*256 + ty*16 + tx
    int tile = blk & 255;
    int n = blk >> 8;
    int ty0 = (tile >> 4) * 16;
    int tx0 = (tile & 15) * 16;

    int tid = threadIdx.x;
    int lane = tid & 63;
    int w = tid >> 6;
    int wf = w >> 2;                      // f-half (0..1)
    int wp = w & 3;                       // px-quarter (0..3): rows wp*4..wp*4+3
    int lr = lane & 15;                   // frag row/col index
    int lk = lane >> 4;                   // frag K group (0..3)

    // ---- stage x tile (once): fp32 global -> bf16 LDS [pix][ch], swizzled
    const float* xb = x + (size_t)n * CC * HW;
    for (int e = tid; e < 324 * 32; e += 512) {
        int c2 = e / 324;
        int pix = e - c2 * 324;
        int hy = pix / 18;
        int hx = pix - hy * 18;
        int gy = clampi(ty0 - 1 + hy, 0, HH - 1);
        int gx = clampi(tx0 - 1 + hx, 0, WW - 1);
        size_t gi = (size_t)(2 * c2) * HW + (size_t)gy * WW + gx;
        unsigned v = packbf(xb[gi], xb[gi + HW]);
        int addr = pix * 128 + ((c2 * 4) ^ ((pix & 7) << 4));
        *reinterpret_cast<unsigned*>(lds_x + addr) = v;
    }
    // ---- stage W tap 0 into buffer 0
#pragma unroll
    for (int i = 0; i < 2; ++i) {
        int e = tid + i * 512;
        int f = e >> 3, cg = e & 7;
        uint4 v = *reinterpret_cast<const uint4*>(wsW + (f * 64 + cg * 8));
        int addr = (f * 128 + cg * 16) ^ ((f & 7) << 4);
        *reinterpret_cast<uint4*>(lds_w[0] + addr) = v;
    }
    __syncthreads();

    f32x4 acc[4][4] = {};                 // [mt (f tile)][pb (px frag)]

    for (int t = 0; t < 9; ++t) {
        int dy = t / 3, dx = t - 3 * (t / 3);

        // T14: issue next-tap W loads early (consumed after compute)
        uint4 wreg[2];
        if (t < 8) {
#pragma unroll
            for (int i = 0; i < 2; ++i) {
                int e = tid + i * 512;
                int f = e >> 3, cg = e & 7;
                wreg[i] = *reinterpret_cast<const uint4*>(wsW + ((t + 1) * 8192 + f * 64 + cg * 8));
            }
        }

        const unsigned char* wbuf = lds_w[t & 1];
#pragma unroll
        for (int kk = 0; kk < 2; ++kk) {
            int off = kk * 64 + lk * 16;
            bf16x8 a[4], b[4];
#pragma unroll
            for (int mt = 0; mt < 4; ++mt) {
                int f = wf * 64 + mt * 16 + lr;
                int addr = f * 128 + (off ^ ((f & 7) << 4));
                a[mt] = *reinterpret_cast<const bf16x8*>(wbuf + addr);
            }
#pragma unroll
            for (int pb = 0; pb < 4; ++pb) {
                int pix = (wp * 4 + pb + dy) * 18 + (lr + dx);
                int addr = pix * 128 + (off ^ ((pix & 7) << 4));
                b[pb] = *reinterpret_cast<const bf16x8*>(lds_x + addr);
            }
#pragma unroll
            for (int mt = 0; mt < 4; ++mt)
#pragma unroll
                for (int pb = 0; pb < 4; ++pb)
                    acc[mt][pb] = __builtin_amdgcn_mfma_f32_16x16x32_bf16(
                        a[mt], b[pb], acc[mt][pb], 0, 0, 0);
        }

        // write next-tap W slab into the other buffer
        if (t < 8) {
#pragma unroll
            for (int i = 0; i < 2; ++i) {
                int e = tid + i * 512;
                int f = e >> 3, cg = e & 7;
                int addr = (f * 128 + cg * 16) ^ ((f & 7) << 4);
                *reinterpret_cast<uint4*>(lds_w[(t + 1) & 1] + addr) = wreg[i];
            }
        }
        __syncthreads();
    }

    // ---- epilogue: bias + store. f = wf*64 + mt*16 + lk*4 + i ; px col = lr
#pragma unroll
    for (int mt = 0; mt < 4; ++mt) {
#pragma unroll
        for (int i = 0; i < 4; ++i) {
            int f = wf * 64 + mt * 16 + lk * 4 + i;
            float bv = bl[f];
            size_t ob = ((size_t)(n * OUTC) + 256 + f) * HW;
#pragma unroll
            for (int pb = 0; pb < 4; ++pb) {
                int r = wp * 4 + pb;
                out[ob + (size_t)(ty0 + r) * WW + (tx0 + lr)] = acc[mt][pb][i] + bv;
            }
        }
    }
}

extern "C" void kernel_launch(void* const* d_in, const int* in_sizes, int n_in,
                              void* d_out, int out_size, void* d_ws, size_t ws_size,
                              hipStream_t stream) {
    const float* x  = (const float*)d_in[0];
    const float* Wl = (const float*)d_in[1];
    const float* bl = (const float*)d_in[2];
    float* out = (float*)d_out;

    wT_kernel<<<144, 256, 0, stream>>>(Wl, (unsigned*)d_ws);
    dw_kernel<<<NN * CC * (HH / 4), 256, 0, stream>>>(x, out);
    learned_kernel<<<NN * 256, 512, 0, stream>>>(x, (const unsigned short*)d_ws, bl, out);
}